// Round 10
// baseline (72.057 us; speedup 1.0000x reference)
//
#include <hip/hip_runtime.h>
#include <hip/hip_bf16.h>
#include <hip/hip_fp16.h>

#define NN 50000
#define NE 800000
#define C 128
#define HH 64
#define TIN 288
#define LN_EPS 1e-5f

typedef __attribute__((ext_vector_type(8))) short bf16x8;
typedef __attribute__((ext_vector_type(4))) float f32x4;
typedef __attribute__((ext_vector_type(2))) float f32x2;
typedef __attribute__((ext_vector_type(4))) int i32x4;

// ws layout (bytes)
//   [0,256)             s[64] f32   (column sums of W1p over all 288 rows)
//   [256,512)           c[64] f32   (ln_b·W1 + b1)
//   [512,2560)          et_tab [16][64] bf16, LINEAR
//   [2560,35328)        B1frag: [kt=8][c=4][lane=64][j=8] bf16 (32768 B)
//   [35328,37376)       B2frag: [kt=2][lane=64][j=8] bf16 (2048 B)
//   [37376,38400)       ohu [8][64] bf16  (W1p rows 256..263)
//   [38400,39424)       ohv [8][64] bf16  (W1p rows 264..271)
//   [39424,239424)      SQ __half2[50000] (per-node sum, sumsq of f32 x)
//   [439424,3639424)    u8 fp8[50000][64]  (PERMUTED row layout, see below)
//   [3639424,6839424)   v8 fp8[50000][64]
// Permutation: byte pos 16q+o (o<8) holds dim 8q+o; pos 16q+8+o holds dim 32+8q+o.
// => lane g's 16 needed dims = one 16B chunk at offset 16g.
#define ETT_OFF 512
#define B1F_OFF 2560
#define B2F_OFF 35328
#define OHU_OFF 37376
#define OHV_OFF 38400
#define SQ_OFF 39424
#define U_OFF 439424
#define V_OFF 3639424

__device__ __forceinline__ short f2bf(float f) {
    __hip_bfloat16 h = __float2bfloat16(f);
    return __builtin_bit_cast(short, h);
}
__device__ __forceinline__ float bf2f(short s) {
    unsigned int u = ((unsigned int)(unsigned short)s) << 16;
    return __builtin_bit_cast(float, u);
}

__global__ void prep_weights(const float* __restrict__ ln_w,
                             const float* __restrict__ ln_b,
                             const float* __restrict__ W1,
                             const float* __restrict__ b1,
                             const float* __restrict__ W2,
                             float* __restrict__ ws) {
    __shared__ float rs[256], rc[256];
    int tid = threadIdx.x;
    int gid = blockIdx.x * 256 + tid;  // 32 blocks x 256
    if (blockIdx.x == 0) {
        // parallel s/c: 4 k-parts x 64 columns
        int col = tid & 63, part = tid >> 6;
        float s = 0.f, c = 0.f;
        for (int k = part * 72; k < part * 72 + 72; ++k) {
            float w = W1[k * HH + col];
            s += ln_w[k] * w;
            c += ln_b[k] * w;
        }
        rs[tid] = s; rc[tid] = c;
        __syncthreads();
        if (tid < 64) {
            float ss = rs[tid] + rs[64 + tid] + rs[128 + tid] + rs[192 + tid];
            float cc = rc[tid] + rc[64 + tid] + rc[128 + tid] + rc[192 + tid];
            ws[tid] = ss;
            ws[64 + tid] = cc + b1[tid];
        }
    }
    short* B1 = (short*)((char*)ws + B1F_OFF);
    for (int idx = gid; idx < 16384; idx += 8192) {
        int j = idx & 7, l = (idx >> 3) & 63, cc = (idx >> 9) & 3, kt = idx >> 11;
        int g = l >> 4, m = l & 15;
        int k = 32 * kt + 8 * g + j, n = 16 * cc + m;
        B1[idx] = f2bf(ln_w[k] * W1[k * HH + n]);
    }
    short* B2 = (short*)((char*)ws + B2F_OFF);
    for (int idx = gid; idx < 1024; idx += 8192) {
        int j = idx & 7, l = (idx >> 3) & 63, kt = idx >> 9;
        int g = l >> 4, m = l & 15;
        int k = 32 * kt + 8 * g + j;
        B2[idx] = f2bf(W2[k * 16 + m]);
    }
    short* ohu = (short*)((char*)ws + OHU_OFF);
    short* ohv = (short*)((char*)ws + OHV_OFF);
    for (int idx = gid; idx < 512; idx += 8192) {
        int t = idx >> 6, j = idx & 63;
        ohu[idx] = f2bf(ln_w[256 + t] * W1[(256 + t) * HH + j]);
        ohv[idx] = f2bf(ln_w[264 + t] * W1[(264 + t) * HH + j]);
    }
    short* ett = (short*)((char*)ws + ETT_OFF);
    for (int idx = gid; idx < 1024; idx += 8192) {
        int et = idx >> 6, j = idx & 63;
        ett[idx] = f2bf(ln_w[272 + et] * W1[(272 + et) * HH + j]);  // LINEAR
    }
}

// per-node: u = x·W1p[0:128] + ohu[ntype], v = x·W1p[128:256] + ohv[ntype]
// stored as fp8 e4m3 permuted rows; SQ = packed half2 (sum, sumsq) of f32 x row.
__global__ __launch_bounds__(512) void node_uv(const float* __restrict__ x,
                                               const int* __restrict__ ntype,
                                               float* __restrict__ ws) {
    // LDS: B1 staging 32KB | 8 waves * 1KB fp8 transpose buffers
    __shared__ __align__(16) char lds_n[32768 + 8192];
    int tid = threadIdx.x;
    {
        const f32x4* src = (const f32x4*)((const char*)ws + B1F_OFF);
        f32x4* dst = (f32x4*)lds_n;
        for (int i = tid; i < 2048; i += 512) dst[i] = src[i];
    }
    __syncthreads();

    int wave = tid >> 6, lane = tid & 63, m = lane & 15, g = lane >> 4;
    int tile = blockIdx.x * 128 + wave * 16;
    int n = tile + m;
    int nc = n < NN ? n : NN - 1;

    float sum = 0.f, sq = 0.f;
    bf16x8 a[4];
#pragma unroll
    for (int kt = 0; kt < 4; ++kt) {
        const float* p = x + (size_t)nc * C + kt * 32 + g * 8;
        f32x4 p0 = __builtin_nontemporal_load((const f32x4*)p);
        f32x4 p1 = __builtin_nontemporal_load((const f32x4*)(p + 4));
        float vv[8] = {p0[0], p0[1], p0[2], p0[3], p1[0], p1[1], p1[2], p1[3]};
#pragma unroll
        for (int j = 0; j < 8; ++j) {
            sum += vv[j];
            sq = fmaf(vv[j], vv[j], sq);
            a[kt][j] = f2bf(vv[j]);
        }
    }
    sum += __shfl_xor(sum, 16); sum += __shfl_xor(sum, 32);
    sq  += __shfl_xor(sq, 16);  sq  += __shfl_xor(sq, 32);
    if (g == 0 && n < NN) {
        __half2 hp;
        hp.x = __float2half(sum);
        hp.y = __float2half(sq);
        ((__half2*)((char*)ws + SQ_OFF))[n] = hp;
    }

    f32x4 au[4], av[4];
#pragma unroll
    for (int cc = 0; cc < 4; ++cc) { au[cc] = (f32x4){0,0,0,0}; av[cc] = (f32x4){0,0,0,0}; }
#pragma unroll
    for (int kt = 0; kt < 4; ++kt) {
        const bf16x8* Bu = (const bf16x8*)(lds_n + (kt * 4) * 1024);
        const bf16x8* Bv = (const bf16x8*)(lds_n + ((kt + 4) * 4) * 1024);
#pragma unroll
        for (int cc = 0; cc < 4; ++cc) {
            au[cc] = __builtin_amdgcn_mfma_f32_16x16x32_bf16(a[kt], Bu[cc * 64 + lane], au[cc], 0, 0, 0);
            av[cc] = __builtin_amdgcn_mfma_f32_16x16x32_bf16(a[kt], Bv[cc * 64 + lane], av[cc], 0, 0, 0);
        }
    }

    int ntv[4];
#pragma unroll
    for (int i = 0; i < 4; ++i) {
        int nn = tile + 4 * g + i;
        ntv[i] = ntype[nn < NN ? nn : NN - 1];
    }
    const unsigned short* ohu = (const unsigned short*)((const char*)ws + OHU_OFF);
    const unsigned short* ohv = (const unsigned short*)((const char*)ws + OHV_OFF);
    char* u8 = (char*)ws + U_OFF;
    char* v8 = (char*)ws + V_OFF;
    char* tb8 = lds_n + 32768 + wave * 1024;
    int nst = tile + m;
    int k2 = m >> 2;  // writer-g of node m (for swizzle inversion)

    // ---- u: fp8-encode into permuted positions, swizzled LDS, coalesced store
#pragma unroll
    for (int cc = 0; cc < 4; ++cc)
#pragma unroll
        for (int i = 0; i < 4; ++i) {
            float val = au[cc][i] + bf2f((short)ohu[ntv[i] * 64 + 16 * cc + m]);
            int d = 16 * cc + m;
            int pos = (d < 32) ? (16 * (d >> 3) + (d & 7))
                               : (16 * ((d - 32) >> 3) + 8 + ((d - 32) & 7));
            pos ^= (g << 4);  // swizzle q-field by writer g (bank spread)
            int pk = __builtin_amdgcn_cvt_pk_fp8_f32(val, val, 0, false);
            tb8[(4 * g + i) * 64 + pos] = (char)(pk & 0xFF);
        }
    if (nst < NN) {
        i32x4 val = *(const i32x4*)(tb8 + m * 64 + 16 * (g ^ k2));
        *(i32x4*)(u8 + (size_t)nst * 64 + 16 * g) = val;
    }
    // ---- v (same buffer; same-wave ordering via lgkmcnt)
#pragma unroll
    for (int cc = 0; cc < 4; ++cc)
#pragma unroll
        for (int i = 0; i < 4; ++i) {
            float val = av[cc][i] + bf2f((short)ohv[ntv[i] * 64 + 16 * cc + m]);
            int d = 16 * cc + m;
            int pos = (d < 32) ? (16 * (d >> 3) + (d & 7))
                               : (16 * ((d - 32) >> 3) + 8 + ((d - 32) & 7));
            pos ^= (g << 4);
            int pk = __builtin_amdgcn_cvt_pk_fp8_f32(val, val, 0, false);
            tb8[(4 * g + i) * 64 + pos] = (char)(pk & 0xFF);
        }
    if (nst < NN) {
        i32x4 val = *(const i32x4*)(tb8 + m * 64 + 16 * (g ^ k2));
        *(i32x4*)(v8 + (size_t)nst * 64 + 16 * g) = val;
    }
}

__device__ __forceinline__ void dec4(int w, float* o) {
    f32x2 lo = __builtin_amdgcn_cvt_pk_f32_fp8(w, false);
    f32x2 hi = __builtin_amdgcn_cvt_pk_f32_fp8(w, true);
    o[0] = lo[0]; o[1] = lo[1]; o[2] = hi[0]; o[3] = hi[1];
}

// barrier-free, LDS-free edge kernel: all shared tables are L1/L2-resident
__global__ __launch_bounds__(256, 4) void edge_kernel(
    const int* __restrict__ ei,
    const int* __restrict__ etype,
    const float* __restrict__ ws,
    const float* __restrict__ b2,
    float* __restrict__ out) {
    int tid = threadIdx.x;
    int wave = tid >> 6, lane = tid & 63, m = lane & 15, g = lane >> 4;
    int base = blockIdx.x * 128 + wave * 32;
    int e0 = base + m, e1 = base + 16 + m;

    int row0 = __builtin_nontemporal_load(ei + e0);
    int col0 = __builtin_nontemporal_load(ei + NE + e0);
    int et0  = __builtin_nontemporal_load(etype + e0);
    int row1 = __builtin_nontemporal_load(ei + e1);
    int col1 = __builtin_nontemporal_load(ei + NE + e1);
    int et1  = __builtin_nontemporal_load(etype + e1);

    // ---- issue ALL gathers + constant loads, then pin them in flight
    const __half2* SQ = (const __half2*)((const char*)ws + SQ_OFF);
    __half2 sr0 = SQ[row0], sc0h = SQ[col0];
    __half2 sr1 = SQ[row1], sc1h = SQ[col1];
    const char* u8 = (const char*)ws + U_OFF;
    const char* v8 = (const char*)ws + V_OFF;
    i32x4 u0q = *(const i32x4*)(u8 + (size_t)row0 * 64 + 16 * g);
    i32x4 v0q = *(const i32x4*)(v8 + (size_t)col0 * 64 + 16 * g);
    i32x4 u1q = *(const i32x4*)(u8 + (size_t)row1 * 64 + 16 * g);
    i32x4 v1q = *(const i32x4*)(v8 + (size_t)col1 * 64 + 16 * g);
    // et table (2 KB, L1-resident), linear
    const unsigned short* ettg = (const unsigned short*)((const char*)ws + ETT_OFF);
    bf16x8 T00 = *(const bf16x8*)(ettg + et0 * 64 + 8 * g);
    bf16x8 T01 = *(const bf16x8*)(ettg + et0 * 64 + 32 + 8 * g);
    bf16x8 T10 = *(const bf16x8*)(ettg + et1 * 64 + 8 * g);
    bf16x8 T11 = *(const bf16x8*)(ettg + et1 * 64 + 32 + 8 * g);
    // W2 A-operand fragments (2 KB, L1-resident)
    const bf16x8* W2A = (const bf16x8*)((const char*)ws + B2F_OFF);
    bf16x8 w0 = W2A[lane], w1 = W2A[64 + lane];
    // per-lane LN-fold constants for dims 8g..8g+7 and 32+8g..+7
    f32x4 s00 = *(const f32x4*)(ws + 8 * g);
    f32x4 s01 = *(const f32x4*)(ws + 8 * g + 4);
    f32x4 s10 = *(const f32x4*)(ws + 32 + 8 * g);
    f32x4 s11 = *(const f32x4*)(ws + 36 + 8 * g);
    f32x4 c00 = *(const f32x4*)(ws + 64 + 8 * g);
    f32x4 c01 = *(const f32x4*)(ws + 64 + 8 * g + 4);
    f32x4 c10 = *(const f32x4*)(ws + 96 + 8 * g);
    f32x4 c11 = *(const f32x4*)(ws + 100 + 8 * g);
    f32x4 b2q = *(const f32x4*)(b2 + 4 * g);
    asm volatile("" ::: "memory");  // pin: loads above issue before uses below

#pragma unroll
    for (int t = 0; t < 2; ++t) {
        __half2 sqr = t ? sr1 : sr0, sqc = t ? sc1h : sc0h;
        i32x4 uq = t ? u1q : u0q;
        i32x4 vq = t ? v1q : v0q;
        bf16x8 T0 = t ? T10 : T00, T1 = t ? T11 : T01;

        float uf[16], vf[16];
        dec4(uq[0], uf); dec4(uq[1], uf + 4); dec4(uq[2], uf + 8); dec4(uq[3], uf + 12);
        dec4(vq[0], vf); dec4(vq[1], vf + 4); dec4(vq[2], vf + 8); dec4(vq[3], vf + 12);

        float sums = __half2float(sqr.x) + __half2float(sqc.x) + 3.0f;
        float sqs  = __half2float(sqr.y) + __half2float(sqc.y) + 3.0f;
        float mu = sums * (1.0f / TIN);
        float var = sqs * (1.0f / TIN) - mu * mu;
        float rstd = rsqrtf(var + LN_EPS);
        float rm = rstd * mu;

        bf16x8 af0, af1;
#pragma unroll
        for (int j = 0; j < 4; ++j) {
            float tt = uf[j] + vf[j] + bf2f(T0[j]);
            float h = fmaf(rstd, tt, fmaf(-rm, s00[j], c00[j]));
            af0[j] = f2bf(fmaxf(h, 0.f));
            float tt2 = uf[j + 4] + vf[j + 4] + bf2f(T0[j + 4]);
            float h2 = fmaf(rstd, tt2, fmaf(-rm, s01[j], c01[j]));
            af0[j + 4] = f2bf(fmaxf(h2, 0.f));
            float tt3 = uf[j + 8] + vf[j + 8] + bf2f(T1[j]);
            float h3 = fmaf(rstd, tt3, fmaf(-rm, s10[j], c10[j]));
            af1[j] = f2bf(fmaxf(h3, 0.f));
            float tt4 = uf[j + 12] + vf[j + 12] + bf2f(T1[j + 4]);
            float h4 = fmaf(rstd, tt4, fmaf(-rm, s11[j], c11[j]));
            af1[j + 4] = f2bf(fmaxf(h4, 0.f));
        }

        // swapped GEMM2: lane holds out-dims 4g..4g+3 of edge base+16t+m.
        f32x4 o = {0.f, 0.f, 0.f, 0.f};
        o = __builtin_amdgcn_mfma_f32_16x16x32_bf16(w0, af0, o, 0, 0, 0);
        o = __builtin_amdgcn_mfma_f32_16x16x32_bf16(w1, af1, o, 0, 0, 0);

        float v0 = o[0] + b2q[0], v1 = o[1] + b2q[1];
        float v2 = o[2] + b2q[2], v3 = o[3] + b2q[3];
        float mx = fmaxf(fmaxf(v0, v1), fmaxf(v2, v3));
        float x0 = __expf(v0 - mx), x1 = __expf(v1 - mx);
        float x2 = __expf(v2 - mx), x3 = __expf(v3 - mx);
        float inv = 1.0f / (x0 + x1 + x2 + x3);
        f32x4 res;
        res[0] = (g == 0 ? 1.0f : 0.0f) - x0 * inv;
        res[1] = (g == 1 ? 1.0f : 0.0f) - x1 * inv;
        res[2] = (g == 2 ? 1.0f : 0.0f) - x2 * inv;
        res[3] = (g == 3 ? 1.0f : 0.0f) - x3 * inv;
        __builtin_nontemporal_store(res, (f32x4*)(out + (size_t)(base + 16 * t + m) * 16 + 4 * g));
    }
}

extern "C" void kernel_launch(void* const* d_in, const int* in_sizes, int n_in,
                              void* d_out, int out_size, void* d_ws, size_t ws_size,
                              hipStream_t stream) {
    const float* x     = (const float*)d_in[0];
    const int*   ei    = (const int*)d_in[1];
    const int*   etype = (const int*)d_in[2];
    const int*   ntype = (const int*)d_in[3];
    const float* ln_w  = (const float*)d_in[4];
    const float* ln_b  = (const float*)d_in[5];
    const float* W1    = (const float*)d_in[6];
    const float* b1    = (const float*)d_in[7];
    const float* W2    = (const float*)d_in[8];
    const float* b2    = (const float*)d_in[9];
    float* out = (float*)d_out;
    float* ws  = (float*)d_ws;

    prep_weights<<<32, 256, 0, stream>>>(ln_w, ln_b, W1, b1, W2, ws);
    node_uv<<<(NN + 127) / 128, 512, 0, stream>>>(x, ntype, ws);
    edge_kernel<<<NE / 128, 256, 0, stream>>>(ei, etype, ws, b2, out);
}

// Round 11
// 66.283 us; speedup vs baseline: 1.0871x; 1.0871x over previous
//
#include <hip/hip_runtime.h>
#include <hip/hip_bf16.h>
#include <hip/hip_fp16.h>

#define NN 50000
#define NE 800000
#define C 128
#define HH 64
#define TIN 288
#define LN_EPS 1e-5f

typedef __attribute__((ext_vector_type(8))) short bf16x8;
typedef __attribute__((ext_vector_type(4))) float f32x4;
typedef __attribute__((ext_vector_type(2))) float f32x2;
typedef __attribute__((ext_vector_type(4))) int i32x4;

// ws layout (bytes)
//   [0,256)             s[64] f32   (column sums of W1p over all 288 rows)
//   [256,512)           c[64] f32   (ln_b·W1 + b1)
//   [512,2560)          et_tab [16][64] bf16, XOR-swizzled 16B units
//   [2560,35328)        B1frag: [kt=8][c=4][lane=64][j=8] bf16 (32768 B)
//   [35328,37376)       B2frag: [kt=2][lane=64][j=8] bf16 (2048 B)
//   [37376,38400)       ohu [8][64] bf16  (W1p rows 256..263)
//   [38400,39424)       ohv [8][64] bf16  (W1p rows 264..271)
//   [39424,239424)      SQ __half2[50000] (per-node sum, sumsq of f32 x)
//   [439424,3639424)    u8 fp8[50000][64]  (PERMUTED row layout, see below)
//   [3639424,6839424)   v8 fp8[50000][64]
// Permutation: byte pos 16q+o (o<8) holds dim 8q+o; pos 16q+8+o holds dim 32+8q+o.
// => lane g's 16 needed dims = one 16B chunk at offset 16g.
#define ETT_OFF 512
#define B1F_OFF 2560
#define B2F_OFF 35328
#define OHU_OFF 37376
#define OHV_OFF 38400
#define SQ_OFF 39424
#define U_OFF 439424
#define V_OFF 3639424

__device__ __forceinline__ short f2bf(float f) {
    __hip_bfloat16 h = __float2bfloat16(f);
    return __builtin_bit_cast(short, h);
}
__device__ __forceinline__ float bf2f(short s) {
    unsigned int u = ((unsigned int)(unsigned short)s) << 16;
    return __builtin_bit_cast(float, u);
}

__global__ void prep_weights(const float* __restrict__ ln_w,
                             const float* __restrict__ ln_b,
                             const float* __restrict__ W1,
                             const float* __restrict__ b1,
                             const float* __restrict__ W2,
                             float* __restrict__ ws) {
    __shared__ float rs[256], rc[256];
    int tid = threadIdx.x;
    int gid = blockIdx.x * 256 + tid;  // 32 blocks x 256
    if (blockIdx.x == 0) {
        // parallel s/c: 4 k-parts x 64 columns
        int col = tid & 63, part = tid >> 6;
        float s = 0.f, c = 0.f;
        for (int k = part * 72; k < part * 72 + 72; ++k) {
            float w = W1[k * HH + col];
            s += ln_w[k] * w;
            c += ln_b[k] * w;
        }
        rs[tid] = s; rc[tid] = c;
        __syncthreads();
        if (tid < 64) {
            float ss = rs[tid] + rs[64 + tid] + rs[128 + tid] + rs[192 + tid];
            float cc = rc[tid] + rc[64 + tid] + rc[128 + tid] + rc[192 + tid];
            ws[tid] = ss;
            ws[64 + tid] = cc + b1[tid];
        }
    }
    short* B1 = (short*)((char*)ws + B1F_OFF);
    for (int idx = gid; idx < 16384; idx += 8192) {
        int j = idx & 7, l = (idx >> 3) & 63, cc = (idx >> 9) & 3, kt = idx >> 11;
        int g = l >> 4, m = l & 15;
        int k = 32 * kt + 8 * g + j, n = 16 * cc + m;
        B1[idx] = f2bf(ln_w[k] * W1[k * HH + n]);
    }
    short* B2 = (short*)((char*)ws + B2F_OFF);
    for (int idx = gid; idx < 1024; idx += 8192) {
        int j = idx & 7, l = (idx >> 3) & 63, kt = idx >> 9;
        int g = l >> 4, m = l & 15;
        int k = 32 * kt + 8 * g + j;
        B2[idx] = f2bf(W2[k * 16 + m]);
    }
    short* ohu = (short*)((char*)ws + OHU_OFF);
    short* ohv = (short*)((char*)ws + OHV_OFF);
    for (int idx = gid; idx < 512; idx += 8192) {
        int t = idx >> 6, j = idx & 63;
        ohu[idx] = f2bf(ln_w[256 + t] * W1[(256 + t) * HH + j]);
        ohv[idx] = f2bf(ln_w[264 + t] * W1[(264 + t) * HH + j]);
    }
    short* ett = (short*)((char*)ws + ETT_OFF);
    for (int idx = gid; idx < 1024; idx += 8192) {
        int et = idx >> 6, j = idx & 63;
        int unit = (j >> 3) ^ (et & 7);  // bank-conflict swizzle on 16B units
        ett[et * 64 + unit * 8 + (j & 7)] = f2bf(ln_w[272 + et] * W1[(272 + et) * HH + j]);
    }
}

// per-node: u = x·W1p[0:128] + ohu[ntype], v = x·W1p[128:256] + ohv[ntype]
// stored as fp8 e4m3 permuted rows; SQ = packed half2 (sum, sumsq) of f32 x row.
__global__ __launch_bounds__(512) void node_uv(const float* __restrict__ x,
                                               const int* __restrict__ ntype,
                                               float* __restrict__ ws) {
    // LDS: B1 staging 32KB | 8 waves * 1KB fp8 transpose buffers
    __shared__ __align__(16) char lds_n[32768 + 8192];
    int tid = threadIdx.x;
    {
        const f32x4* src = (const f32x4*)((const char*)ws + B1F_OFF);
        f32x4* dst = (f32x4*)lds_n;
        for (int i = tid; i < 2048; i += 512) dst[i] = src[i];
    }
    __syncthreads();

    int wave = tid >> 6, lane = tid & 63, m = lane & 15, g = lane >> 4;
    int tile = blockIdx.x * 128 + wave * 16;
    int n = tile + m;
    int nc = n < NN ? n : NN - 1;

    float sum = 0.f, sq = 0.f;
    bf16x8 a[4];
#pragma unroll
    for (int kt = 0; kt < 4; ++kt) {
        const float* p = x + (size_t)nc * C + kt * 32 + g * 8;
        f32x4 p0 = __builtin_nontemporal_load((const f32x4*)p);
        f32x4 p1 = __builtin_nontemporal_load((const f32x4*)(p + 4));
        float vv[8] = {p0[0], p0[1], p0[2], p0[3], p1[0], p1[1], p1[2], p1[3]};
#pragma unroll
        for (int j = 0; j < 8; ++j) {
            sum += vv[j];
            sq = fmaf(vv[j], vv[j], sq);
            a[kt][j] = f2bf(vv[j]);
        }
    }
    sum += __shfl_xor(sum, 16); sum += __shfl_xor(sum, 32);
    sq  += __shfl_xor(sq, 16);  sq  += __shfl_xor(sq, 32);
    if (g == 0 && n < NN) {
        __half2 hp;
        hp.x = __float2half(sum);
        hp.y = __float2half(sq);
        ((__half2*)((char*)ws + SQ_OFF))[n] = hp;
    }

    f32x4 au[4], av[4];
#pragma unroll
    for (int cc = 0; cc < 4; ++cc) { au[cc] = (f32x4){0,0,0,0}; av[cc] = (f32x4){0,0,0,0}; }
#pragma unroll
    for (int kt = 0; kt < 4; ++kt) {
        const bf16x8* Bu = (const bf16x8*)(lds_n + (kt * 4) * 1024);
        const bf16x8* Bv = (const bf16x8*)(lds_n + ((kt + 4) * 4) * 1024);
#pragma unroll
        for (int cc = 0; cc < 4; ++cc) {
            au[cc] = __builtin_amdgcn_mfma_f32_16x16x32_bf16(a[kt], Bu[cc * 64 + lane], au[cc], 0, 0, 0);
            av[cc] = __builtin_amdgcn_mfma_f32_16x16x32_bf16(a[kt], Bv[cc * 64 + lane], av[cc], 0, 0, 0);
        }
    }

    int ntv[4];
#pragma unroll
    for (int i = 0; i < 4; ++i) {
        int nn = tile + 4 * g + i;
        ntv[i] = ntype[nn < NN ? nn : NN - 1];
    }
    const unsigned short* ohu = (const unsigned short*)((const char*)ws + OHU_OFF);
    const unsigned short* ohv = (const unsigned short*)((const char*)ws + OHV_OFF);
    char* u8 = (char*)ws + U_OFF;
    char* v8 = (char*)ws + V_OFF;
    char* tb8 = lds_n + 32768 + wave * 1024;
    int nst = tile + m;
    int k2 = m >> 2;  // writer-g of node m (for swizzle inversion)

    // ---- u: fp8-encode into permuted positions, swizzled LDS, coalesced store
#pragma unroll
    for (int cc = 0; cc < 4; ++cc)
#pragma unroll
        for (int i = 0; i < 4; ++i) {
            float val = au[cc][i] + bf2f((short)ohu[ntv[i] * 64 + 16 * cc + m]);
            int d = 16 * cc + m;
            int pos = (d < 32) ? (16 * (d >> 3) + (d & 7))
                               : (16 * ((d - 32) >> 3) + 8 + ((d - 32) & 7));
            pos ^= (g << 4);  // swizzle q-field by writer g (bank spread)
            int pk = __builtin_amdgcn_cvt_pk_fp8_f32(val, val, 0, false);
            tb8[(4 * g + i) * 64 + pos] = (char)(pk & 0xFF);
        }
    if (nst < NN) {
        i32x4 val = *(const i32x4*)(tb8 + m * 64 + 16 * (g ^ k2));
        *(i32x4*)(u8 + (size_t)nst * 64 + 16 * g) = val;
    }
    // ---- v (same buffer; same-wave ordering via lgkmcnt)
#pragma unroll
    for (int cc = 0; cc < 4; ++cc)
#pragma unroll
        for (int i = 0; i < 4; ++i) {
            float val = av[cc][i] + bf2f((short)ohv[ntv[i] * 64 + 16 * cc + m]);
            int d = 16 * cc + m;
            int pos = (d < 32) ? (16 * (d >> 3) + (d & 7))
                               : (16 * ((d - 32) >> 3) + 8 + ((d - 32) & 7));
            pos ^= (g << 4);
            int pk = __builtin_amdgcn_cvt_pk_fp8_f32(val, val, 0, false);
            tb8[(4 * g + i) * 64 + pos] = (char)(pk & 0xFF);
        }
    if (nst < NN) {
        i32x4 val = *(const i32x4*)(tb8 + m * 64 + 16 * (g ^ k2));
        *(i32x4*)(v8 + (size_t)nst * 64 + 16 * g) = val;
    }
}

__device__ __forceinline__ void dec4(int w, float* o) {
    f32x2 lo = __builtin_amdgcn_cvt_pk_f32_fp8(w, false);
    f32x2 hi = __builtin_amdgcn_cvt_pk_f32_fp8(w, true);
    o[0] = lo[0]; o[1] = lo[1]; o[2] = hi[0]; o[3] = hi[1];
}

__global__ __launch_bounds__(512) void edge_kernel(
    const int* __restrict__ ei,
    const int* __restrict__ etype,
    const float* __restrict__ ws,
    const float* __restrict__ b2,
    float* __restrict__ out) {
    // LDS: W2A frag (A-operand of swapped GEMM2) [0,1024) shorts | et_tab [1024,2048)
    __shared__ __align__(16) short lds_e[2048];
    int tid = threadIdx.x;
    int wave = tid >> 6, lane = tid & 63, m = lane & 15, g = lane >> 4;
    int base = blockIdx.x * 256 + wave * 32;
    int e0 = base + m, e1 = base + 16 + m;

    int row0 = __builtin_nontemporal_load(ei + e0);
    int col0 = __builtin_nontemporal_load(ei + NE + e0);
    int et0  = __builtin_nontemporal_load(etype + e0);
    int row1 = __builtin_nontemporal_load(ei + e1);
    int col1 = __builtin_nontemporal_load(ei + NE + e1);
    int et1  = __builtin_nontemporal_load(etype + e1);

    if (tid < 128)
        ((f32x4*)lds_e)[tid] = *(const f32x4*)((const char*)ws + B2F_OFF + tid * 16);
    else if (tid < 256)
        ((f32x4*)lds_e)[tid] = *(const f32x4*)((const char*)ws + ETT_OFF + (tid - 128) * 16);
    __syncthreads();

    // ---- issue ALL gathers + constant loads, then pin them in flight
    const __half2* SQ = (const __half2*)((const char*)ws + SQ_OFF);
    __half2 sr0 = SQ[row0], sc0h = SQ[col0];
    __half2 sr1 = SQ[row1], sc1h = SQ[col1];
    const char* u8 = (const char*)ws + U_OFF;
    const char* v8 = (const char*)ws + V_OFF;
    i32x4 u0q = *(const i32x4*)(u8 + (size_t)row0 * 64 + 16 * g);
    i32x4 v0q = *(const i32x4*)(v8 + (size_t)col0 * 64 + 16 * g);
    i32x4 u1q = *(const i32x4*)(u8 + (size_t)row1 * 64 + 16 * g);
    i32x4 v1q = *(const i32x4*)(v8 + (size_t)col1 * 64 + 16 * g);
    // per-lane LN-fold constants for dims 8g..8g+7 and 32+8g..+7
    f32x4 s00 = *(const f32x4*)(ws + 8 * g);
    f32x4 s01 = *(const f32x4*)(ws + 8 * g + 4);
    f32x4 s10 = *(const f32x4*)(ws + 32 + 8 * g);
    f32x4 s11 = *(const f32x4*)(ws + 36 + 8 * g);
    f32x4 c00 = *(const f32x4*)(ws + 64 + 8 * g);
    f32x4 c01 = *(const f32x4*)(ws + 64 + 8 * g + 4);
    f32x4 c10 = *(const f32x4*)(ws + 96 + 8 * g);
    f32x4 c11 = *(const f32x4*)(ws + 100 + 8 * g);
    f32x4 b2q = *(const f32x4*)(b2 + 4 * g);
    asm volatile("" ::: "memory");  // pin: loads above issue before uses below

    const bf16x8* W2A = (const bf16x8*)lds_e;
    bf16x8 w0 = W2A[lane], w1 = W2A[64 + lane];
    const short* ett = lds_e + 1024;

#pragma unroll
    for (int t = 0; t < 2; ++t) {
        int et = t ? et1 : et0;
        __half2 sqr = t ? sr1 : sr0, sqc = t ? sc1h : sc0h;
        i32x4 uq = t ? u1q : u0q;
        i32x4 vq = t ? v1q : v0q;

        bf16x8 T0 = *(const bf16x8*)(ett + et * 64 + ((g ^ (et & 7)) << 3));
        bf16x8 T1 = *(const bf16x8*)(ett + et * 64 + (((4 + g) ^ (et & 7)) << 3));

        float uf[16], vf[16];
        dec4(uq[0], uf); dec4(uq[1], uf + 4); dec4(uq[2], uf + 8); dec4(uq[3], uf + 12);
        dec4(vq[0], vf); dec4(vq[1], vf + 4); dec4(vq[2], vf + 8); dec4(vq[3], vf + 12);

        float sums = __half2float(sqr.x) + __half2float(sqc.x) + 3.0f;
        float sqs  = __half2float(sqr.y) + __half2float(sqc.y) + 3.0f;
        float mu = sums * (1.0f / TIN);
        float var = sqs * (1.0f / TIN) - mu * mu;
        float rstd = rsqrtf(var + LN_EPS);
        float rm = rstd * mu;

        bf16x8 af0, af1;
#pragma unroll
        for (int j = 0; j < 4; ++j) {
            float tt = uf[j] + vf[j] + bf2f(T0[j]);
            float h = fmaf(rstd, tt, fmaf(-rm, s00[j], c00[j]));
            af0[j] = f2bf(fmaxf(h, 0.f));
            float tt2 = uf[j + 4] + vf[j + 4] + bf2f(T0[j + 4]);
            float h2 = fmaf(rstd, tt2, fmaf(-rm, s01[j], c01[j]));
            af0[j + 4] = f2bf(fmaxf(h2, 0.f));
            float tt3 = uf[j + 8] + vf[j + 8] + bf2f(T1[j]);
            float h3 = fmaf(rstd, tt3, fmaf(-rm, s10[j], c10[j]));
            af1[j] = f2bf(fmaxf(h3, 0.f));
            float tt4 = uf[j + 12] + vf[j + 12] + bf2f(T1[j + 4]);
            float h4 = fmaf(rstd, tt4, fmaf(-rm, s11[j], c11[j]));
            af1[j + 4] = f2bf(fmaxf(h4, 0.f));
        }

        // swapped GEMM2: lane holds out-dims 4g..4g+3 of edge base+16t+m.
        f32x4 o = {0.f, 0.f, 0.f, 0.f};
        o = __builtin_amdgcn_mfma_f32_16x16x32_bf16(w0, af0, o, 0, 0, 0);
        o = __builtin_amdgcn_mfma_f32_16x16x32_bf16(w1, af1, o, 0, 0, 0);

        float v0 = o[0] + b2q[0], v1 = o[1] + b2q[1];
        float v2 = o[2] + b2q[2], v3 = o[3] + b2q[3];
        float mx = fmaxf(fmaxf(v0, v1), fmaxf(v2, v3));
        float x0 = __expf(v0 - mx), x1 = __expf(v1 - mx);
        float x2 = __expf(v2 - mx), x3 = __expf(v3 - mx);
        float inv = 1.0f / (x0 + x1 + x2 + x3);
        f32x4 res;
        res[0] = (g == 0 ? 1.0f : 0.0f) - x0 * inv;
        res[1] = (g == 1 ? 1.0f : 0.0f) - x1 * inv;
        res[2] = (g == 2 ? 1.0f : 0.0f) - x2 * inv;
        res[3] = (g == 3 ? 1.0f : 0.0f) - x3 * inv;
        __builtin_nontemporal_store(res, (f32x4*)(out + (size_t)(base + 16 * t + m) * 16 + 4 * g));
    }
}

extern "C" void kernel_launch(void* const* d_in, const int* in_sizes, int n_in,
                              void* d_out, int out_size, void* d_ws, size_t ws_size,
                              hipStream_t stream) {
    const float* x     = (const float*)d_in[0];
    const int*   ei    = (const int*)d_in[1];
    const int*   etype = (const int*)d_in[2];
    const int*   ntype = (const int*)d_in[3];
    const float* ln_w  = (const float*)d_in[4];
    const float* ln_b  = (const float*)d_in[5];
    const float* W1    = (const float*)d_in[6];
    const float* b1    = (const float*)d_in[7];
    const float* W2    = (const float*)d_in[8];
    const float* b2    = (const float*)d_in[9];
    float* out = (float*)d_out;
    float* ws  = (float*)d_ws;

    prep_weights<<<32, 256, 0, stream>>>(ln_w, ln_b, W1, b1, W2, ws);
    node_uv<<<(NN + 127) / 128, 512, 0, stream>>>(x, ntype, ws);
    edge_kernel<<<NE / 256, 512, 0, stream>>>(ei, etype, ws, b2, out);
}